// Round 3
// baseline (3352.862 us; speedup 1.0000x reference)
//
#include <hip/hip_runtime.h>

#define N_NODES_C 250000
#define F 16
#define N_GRAPHS_C 512
#define BN_EPS 1e-5f

// ---------------------------------------------------------------------------
// Scatter: agg[dst[e]] += h[src[e]]  (one thread per (edge, 4-feature block))
// ---------------------------------------------------------------------------
__global__ __launch_bounds__(256) void k_scatter(
    const float* __restrict__ h, const int* __restrict__ src,
    const int* __restrict__ dst, float* __restrict__ agg, int n_edges)
{
    int idx = blockIdx.x * 256 + threadIdx.x;
    int tot = n_edges << 2;
    if (idx >= tot) return;
    int e = idx >> 2, q = idx & 3;
    int s = src[e], d = dst[e];
    float4 v = reinterpret_cast<const float4*>(h + (size_t)s * F)[q];
    float* o = agg + (size_t)d * F + q * 4;
    atomicAdd(o + 0, v.x);
    atomicAdd(o + 1, v.y);
    atomicAdd(o + 2, v.z);
    atomicAdd(o + 3, v.w);
}

// ---------------------------------------------------------------------------
// Fused MLP (Lin->ReLU->Lin->ReLU) + BN-statistics accumulation.
// One thread per node. Weights staged in LDS.
// stats[0..15] += sum(out_j), stats[16..31] += sum(out_j^2)
// ---------------------------------------------------------------------------
template <int HID>
__global__ __launch_bounds__(256) void k_mlp_stats(
    const float* __restrict__ xin, const float* __restrict__ agg,
    const float* __restrict__ Wa, const float* __restrict__ ba,
    const float* __restrict__ Wb, const float* __restrict__ bb,
    float* __restrict__ hpre, float* __restrict__ stats, int n_nodes)
{
    __shared__ float sWa[F * HID], sba[HID], sWb[HID * F], sbb[F];
    for (int i = threadIdx.x; i < F * HID; i += 256) sWa[i] = Wa[i];
    for (int i = threadIdx.x; i < HID * F; i += 256) sWb[i] = Wb[i];
    if (threadIdx.x < HID) sba[threadIdx.x] = ba[threadIdx.x];
    if (threadIdx.x < F)   sbb[threadIdx.x] = bb[threadIdx.x];
    __syncthreads();

    int node = blockIdx.x * 256 + threadIdx.x;
    float o[F];
    if (node < n_nodes) {
        float v[F];
        const float4* xp = reinterpret_cast<const float4*>(xin + (size_t)node * F);
        const float4* ap = reinterpret_cast<const float4*>(agg + (size_t)node * F);
#pragma unroll
        for (int q = 0; q < 4; q++) {
            float4 a = xp[q], b = ap[q];
            v[q * 4 + 0] = a.x + b.x;
            v[q * 4 + 1] = a.y + b.y;
            v[q * 4 + 2] = a.z + b.z;
            v[q * 4 + 3] = a.w + b.w;
        }
        float hid[HID];
#pragma unroll
        for (int j = 0; j < HID; j++) hid[j] = sba[j];
#pragma unroll
        for (int k = 0; k < F; k++) {
            float vk = v[k];
#pragma unroll
            for (int j = 0; j < HID; j++) hid[j] = fmaf(vk, sWa[k * HID + j], hid[j]);
        }
#pragma unroll
        for (int j = 0; j < HID; j++) hid[j] = fmaxf(hid[j], 0.f);
#pragma unroll
        for (int j = 0; j < F; j++) o[j] = sbb[j];
#pragma unroll
        for (int k = 0; k < HID; k++) {
            float hk = hid[k];
#pragma unroll
            for (int j = 0; j < F; j++) o[j] = fmaf(hk, sWb[k * F + j], o[j]);
        }
#pragma unroll
        for (int j = 0; j < F; j++) o[j] = fmaxf(o[j], 0.f);
        float4* op = reinterpret_cast<float4*>(hpre + (size_t)node * F);
        op[0] = make_float4(o[0], o[1], o[2], o[3]);
        op[1] = make_float4(o[4], o[5], o[6], o[7]);
        op[2] = make_float4(o[8], o[9], o[10], o[11]);
        op[3] = make_float4(o[12], o[13], o[14], o[15]);
    } else {
#pragma unroll
        for (int j = 0; j < F; j++) o[j] = 0.f;
    }

    // per-wave shuffle reduce (64 lanes) of sum and sumsq for 16 features
    __shared__ float red[4][2 * F];
    int lane = threadIdx.x & 63, wid = threadIdx.x >> 6;
#pragma unroll
    for (int j = 0; j < F; j++) {
        float s = o[j], ss = o[j] * o[j];
#pragma unroll
        for (int off = 32; off; off >>= 1) {
            s  += __shfl_down(s, off);
            ss += __shfl_down(ss, off);
        }
        if (lane == 0) { red[wid][j] = s; red[wid][F + j] = ss; }
    }
    __syncthreads();
    if (threadIdx.x < 2 * F) {
        float t = red[0][threadIdx.x] + red[1][threadIdx.x] +
                  red[2][threadIdx.x] + red[3][threadIdx.x];
        atomicAdd(&stats[threadIdx.x], t);
    }
}

// ---------------------------------------------------------------------------
// BN (training-mode batch stats, biased var) + ReLU, elementwise.
// One thread per float4 (4 consecutive features).
// ---------------------------------------------------------------------------
__global__ __launch_bounds__(256) void k_bn_relu(
    const float* __restrict__ hpre, const float* __restrict__ stats,
    const float* __restrict__ gamma, const float* __restrict__ beta,
    float* __restrict__ hout, int n_nodes)
{
    int idx = blockIdx.x * 256 + threadIdx.x;
    int tot = n_nodes * 4;
    if (idx >= tot) return;
    int q = idx & 3;
    float4 v = reinterpret_cast<const float4*>(hpre)[idx];
    float invN = 1.f / (float)n_nodes;
    float r[4];
    float vin[4] = {v.x, v.y, v.z, v.w};
#pragma unroll
    for (int t = 0; t < 4; t++) {
        int j = q * 4 + t;
        float mean = stats[j] * invN;
        float var  = stats[F + j] * invN - mean * mean;
        float sc   = gamma[j] * rsqrtf(var + BN_EPS);
        r[t] = fmaxf((vin[t] - mean) * sc + beta[j], 0.f);
    }
    reinterpret_cast<float4*>(hout)[idx] = make_float4(r[0], r[1], r[2], r[3]);
}

// ---------------------------------------------------------------------------
// Per-graph max/mean pool + final FC. One block per graph (batch is sorted).
// Post-ReLU h >= 0, so max-init 0 reproduces the empty-segment guard.
// ---------------------------------------------------------------------------
__global__ __launch_bounds__(256) void k_pool_fc(
    const float* __restrict__ h, const int* __restrict__ batch,
    const float* __restrict__ Wfc, const float* __restrict__ bfc,
    float* __restrict__ out, int n_nodes)
{
    int g = blockIdx.x;
    // lower_bound(batch, g) and lower_bound(batch, g+1)
    int lo = 0, hi = n_nodes;
    while (lo < hi) { int m = (lo + hi) >> 1; if (batch[m] < g) lo = m + 1; else hi = m; }
    int start = lo;
    hi = n_nodes;
    while (lo < hi) { int m = (lo + hi) >> 1; if (batch[m] < g + 1) lo = m + 1; else hi = m; }
    int end = lo;

    float mx[F], sm[F];
#pragma unroll
    for (int j = 0; j < F; j++) { mx[j] = 0.f; sm[j] = 0.f; }

    for (int i = start + (int)threadIdx.x; i < end; i += 256) {
        const float4* p = reinterpret_cast<const float4*>(h + (size_t)i * F);
#pragma unroll
        for (int q = 0; q < 4; q++) {
            float4 v = p[q];
            mx[q * 4 + 0] = fmaxf(mx[q * 4 + 0], v.x); sm[q * 4 + 0] += v.x;
            mx[q * 4 + 1] = fmaxf(mx[q * 4 + 1], v.y); sm[q * 4 + 1] += v.y;
            mx[q * 4 + 2] = fmaxf(mx[q * 4 + 2], v.z); sm[q * 4 + 2] += v.z;
            mx[q * 4 + 3] = fmaxf(mx[q * 4 + 3], v.w); sm[q * 4 + 3] += v.w;
        }
    }
    // wave reduce
#pragma unroll
    for (int j = 0; j < F; j++) {
#pragma unroll
        for (int off = 32; off; off >>= 1) {
            mx[j] = fmaxf(mx[j], __shfl_down(mx[j], off));
            sm[j] += __shfl_down(sm[j], off);
        }
    }
    __shared__ float rmx[4][F], rsm[4][F];
    int lane = threadIdx.x & 63, wid = threadIdx.x >> 6;
    if (lane == 0) {
#pragma unroll
        for (int j = 0; j < F; j++) { rmx[wid][j] = mx[j]; rsm[wid][j] = sm[j]; }
    }
    __syncthreads();
    if (threadIdx.x == 0) {
        float pooled[2 * F];
        int cnt = end - start;
        float inv = 1.f / (float)(cnt > 0 ? cnt : 1);
#pragma unroll
        for (int j = 0; j < F; j++) {
            float m = fmaxf(fmaxf(rmx[0][j], rmx[1][j]), fmaxf(rmx[2][j], rmx[3][j]));
            float s = rsm[0][j] + rsm[1][j] + rsm[2][j] + rsm[3][j];
            pooled[j]     = m;
            pooled[F + j] = s * inv;
        }
#pragma unroll
        for (int c = 0; c < 2; c++) {
            float acc = bfc[c];
#pragma unroll
            for (int k = 0; k < 2 * F; k++) acc = fmaf(pooled[k], Wfc[k * 2 + c], acc);
            out[g * 2 + c] = acc;
        }
    }
}

extern "C" void kernel_launch(void* const* d_in, const int* in_sizes, int n_in,
                              void* d_out, int out_size, void* d_ws, size_t ws_size,
                              hipStream_t stream) {
    const float* x    = (const float*)d_in[0];
    const float* W1a  = (const float*)d_in[1];
    const float* b1a  = (const float*)d_in[2];
    const float* W1b  = (const float*)d_in[3];
    const float* b1b  = (const float*)d_in[4];
    const float* g1   = (const float*)d_in[5];
    const float* be1  = (const float*)d_in[6];
    const float* W2a  = (const float*)d_in[7];
    const float* b2a  = (const float*)d_in[8];
    const float* W2b  = (const float*)d_in[9];
    const float* b2b  = (const float*)d_in[10];
    const float* g2   = (const float*)d_in[11];
    const float* be2  = (const float*)d_in[12];
    const float* Wfc  = (const float*)d_in[13];
    const float* bfc  = (const float*)d_in[14];
    const int*   eidx = (const int*)d_in[15];
    const int*   batch= (const int*)d_in[16];

    const int n_nodes = in_sizes[0] / F;          // 250000
    const int n_edges = in_sizes[15] / 2;         // 8000000
    const int* src = eidx;
    const int* dst = eidx + n_edges;

    const size_t NB = (size_t)n_nodes * F * sizeof(float); // 16 MB
    char* ws    = (char*)d_ws;
    float* hpre = (float*)(ws);
    float* hbuf = (float*)(ws + NB);
    float* agg  = (float*)(ws + 2 * NB);
    float* stats= (float*)(ws + 3 * NB);
    float* out  = (float*)d_out;

    const int nblk_nodes = (n_nodes + 255) / 256;
    const int nblk_el4   = (n_nodes * 4 + 255) / 256;
    const int nblk_edges = (int)(((long long)n_edges * 4 + 255) / 256);

    // ---- layer 1 ----
    hipMemsetAsync(agg, 0, NB, stream);
    hipMemsetAsync(stats, 0, 2 * F * sizeof(float), stream);
    k_scatter<<<nblk_edges, 256, 0, stream>>>(x, src, dst, agg, n_edges);
    k_mlp_stats<32><<<nblk_nodes, 256, 0, stream>>>(x, agg, W1a, b1a, W1b, b1b,
                                                    hpre, stats, n_nodes);
    k_bn_relu<<<nblk_el4, 256, 0, stream>>>(hpre, stats, g1, be1, hbuf, n_nodes);

    // ---- layer 2 ----
    hipMemsetAsync(agg, 0, NB, stream);
    hipMemsetAsync(stats, 0, 2 * F * sizeof(float), stream);
    k_scatter<<<nblk_edges, 256, 0, stream>>>(hbuf, src, dst, agg, n_edges);
    k_mlp_stats<16><<<nblk_nodes, 256, 0, stream>>>(hbuf, agg, W2a, b2a, W2b, b2b,
                                                    hpre, stats, n_nodes);
    k_bn_relu<<<nblk_el4, 256, 0, stream>>>(hpre, stats, g2, be2, hbuf, n_nodes);

    // ---- pool + fc ----
    k_pool_fc<<<N_GRAPHS_C, 256, 0, stream>>>(hbuf, batch, Wfc, bfc, out, n_nodes);
}

// Round 4
// 1678.029 us; speedup vs baseline: 1.9981x; 1.9981x over previous
//
#include <hip/hip_runtime.h>

#define F 16
#define N_GRAPHS_C 512
#define BN_EPS 1e-5f

#define NBSHIFT 10                   // 1024 nodes per bucket
#define BSZ (1 << NBSHIFT)
#define SRCBITS 18                   // src ids fit 18 bits (250000 < 262144)
#define SRCMASK ((1u << SRCBITS) - 1u)
#define PCHUNK 8192                  // edges per partition block

// ---------------------------------------------------------------------------
// FALLBACK ONLY (small workspace): per-edge global atomics
// ---------------------------------------------------------------------------
__global__ __launch_bounds__(256) void k_scatter(
    const float* __restrict__ h, const int* __restrict__ src,
    const int* __restrict__ dst, float* __restrict__ agg, int n_edges)
{
    int idx = blockIdx.x * 256 + threadIdx.x;
    int tot = n_edges << 2;
    if (idx >= tot) return;
    int e = idx >> 2, q = idx & 3;
    int s = src[e], d = dst[e];
    float4 v = reinterpret_cast<const float4*>(h + (size_t)s * F)[q];
    float* o = agg + (size_t)d * F + q * 4;
    atomicAdd(o + 0, v.x);
    atomicAdd(o + 1, v.y);
    atomicAdd(o + 2, v.z);
    atomicAdd(o + 3, v.w);
}

// ---------------------------------------------------------------------------
// Bucket histogram of dst (bucket = dst >> NBSHIFT). LDS-staged.
// ---------------------------------------------------------------------------
__global__ __launch_bounds__(256) void k_hist(
    const int* __restrict__ dst, int n_edges, unsigned* __restrict__ bucket_cnt,
    int nbk)
{
    __shared__ unsigned h[256];
    for (int i = threadIdx.x; i < nbk; i += 256) h[i] = 0;
    __syncthreads();
    for (int i = blockIdx.x * 256 + threadIdx.x; i < n_edges; i += gridDim.x * 256)
        atomicAdd(&h[dst[i] >> NBSHIFT], 1u);
    __syncthreads();
    for (int i = threadIdx.x; i < nbk; i += 256)
        if (h[i]) atomicAdd(&bucket_cnt[i], h[i]);
}

// ---------------------------------------------------------------------------
// Exclusive scan over nbk buckets (tiny; serial on one thread).
// ---------------------------------------------------------------------------
__global__ void k_scan(const unsigned* __restrict__ cnt,
                       unsigned* __restrict__ bstart,
                       unsigned* __restrict__ cursor, int nbk)
{
    if (blockIdx.x == 0 && threadIdx.x == 0) {
        unsigned run = 0;
        for (int b = 0; b < nbk; b++) { bstart[b] = run; cursor[b] = run; run += cnt[b]; }
        bstart[nbk] = run;
    }
}

// ---------------------------------------------------------------------------
// Partition edges into per-bucket contiguous regions of part[].
// Per chunk: LDS counting sort by bucket -> coalesced run writes.
// packed = src | (dst & (BSZ-1)) << SRCBITS
// ---------------------------------------------------------------------------
__global__ __launch_bounds__(256) void k_partition(
    const int* __restrict__ src, const int* __restrict__ dst, int n_edges,
    unsigned* __restrict__ cursor, unsigned* __restrict__ part, int nbk)
{
    __shared__ unsigned hist[256];
    __shared__ unsigned offs[257];
    __shared__ unsigned lcur[256];
    __shared__ unsigned gbase[256];
    __shared__ unsigned stage[PCHUNK];   // 32 KB

    int base = blockIdx.x * PCHUNK;
    int cnt = n_edges - base; if (cnt > PCHUNK) cnt = PCHUNK;
    if (cnt <= 0) return;

    for (int i = threadIdx.x; i < nbk; i += 256) hist[i] = 0;
    __syncthreads();
    // pass 1: chunk histogram
    for (int i = threadIdx.x; i < cnt; i += 256)
        atomicAdd(&hist[dst[base + i] >> NBSHIFT], 1u);
    __syncthreads();
    if (threadIdx.x == 0) {
        unsigned run = 0;
        for (int b = 0; b < nbk; b++) { offs[b] = run; run += hist[b]; }
        offs[nbk] = run;
    }
    __syncthreads();
    // staging cursors + global reservations
    for (int b = threadIdx.x; b < nbk; b += 256) {
        lcur[b] = offs[b];
        unsigned hb = hist[b];
        gbase[b] = hb ? atomicAdd(&cursor[b], hb) : 0u;
    }
    __syncthreads();
    // pass 2: stage packed edges, sorted by bucket
    for (int i = threadIdx.x; i < cnt; i += 256) {
        int d = dst[base + i];
        int b = d >> NBSHIFT;
        unsigned p = (unsigned)src[base + i] | (((unsigned)d & (BSZ - 1u)) << SRCBITS);
        stage[atomicAdd(&lcur[b], 1u)] = p;
    }
    __syncthreads();
    // write out: consecutive staged positions of one bucket -> consecutive global
    for (int i = threadIdx.x; i < cnt; i += 256) {
        int lo = 0, hi = nbk;                      // offs[lo] <= i < offs[hi]
        while (hi - lo > 1) { int m = (lo + hi) >> 1; if (offs[m] <= (unsigned)i) lo = m; else hi = m; }
        part[gbase[lo] + ((unsigned)i - offs[lo])] = stage[i];
    }
}

// ---------------------------------------------------------------------------
// Aggregate one bucket entirely in LDS (no global atomics).
// tile layout swizzled: feature f of local row dl at tile[dl*16 + ((f+dl)&15)]
// (unswizzled row-major would put every lane's f-th atomic in bank {f,f+16}
//  -> 32-way conflict; swizzle spreads across all 32 banks)
// ---------------------------------------------------------------------------
__global__ __launch_bounds__(1024) void k_aggregate(
    const float* __restrict__ h, const unsigned* __restrict__ part,
    const unsigned* __restrict__ bstart, float* __restrict__ agg, int n_nodes)
{
    __shared__ float tile[BSZ * F];   // 64 KB
    int b = blockIdx.x;
    unsigned s = bstart[b], e = bstart[b + 1];
    for (int i = threadIdx.x; i < BSZ * F; i += 1024) tile[i] = 0.f;
    __syncthreads();

    for (unsigned i = s + threadIdx.x; i < e; i += 1024) {
        unsigned p = part[i];
        unsigned srcn = p & SRCMASK;
        unsigned dl   = p >> SRCBITS;
        const float4* hp = reinterpret_cast<const float4*>(h + (size_t)srcn * F);
        float4 v0 = hp[0], v1 = hp[1], v2 = hp[2], v3 = hp[3];
        float vv[16] = { v0.x, v0.y, v0.z, v0.w, v1.x, v1.y, v1.z, v1.w,
                         v2.x, v2.y, v2.z, v2.w, v3.x, v3.y, v3.z, v3.w };
        float* trow = &tile[dl * F];
#pragma unroll
        for (int k = 0; k < 16; k++)
            atomicAdd(&trow[(k + dl) & 15], vv[k]);
    }
    __syncthreads();

    int node0 = b << NBSHIFT;
    int lim = n_nodes - node0; if (lim > BSZ) lim = BSZ;
    float* aggb = agg + (size_t)node0 * F;
    for (int idx = threadIdx.x; idx < lim * F; idx += 1024) {
        int r = idx >> 4, f = idx & 15;
        aggb[idx] = tile[r * F + ((f + r) & 15)];   // conflict-free unswizzle read
    }
}

// ---------------------------------------------------------------------------
// Fused MLP (Lin->ReLU->Lin->ReLU) + BN-statistics accumulation.
// NOTE: hpre may alias agg (each thread reads then writes only its own row).
// ---------------------------------------------------------------------------
template <int HID>
__global__ __launch_bounds__(256) void k_mlp_stats(
    const float* __restrict__ xin, const float* agg,
    const float* __restrict__ Wa, const float* __restrict__ ba,
    const float* __restrict__ Wb, const float* __restrict__ bb,
    float* hpre, float* __restrict__ stats, int n_nodes)
{
    __shared__ float sWa[F * HID], sba[HID], sWb[HID * F], sbb[F];
    for (int i = threadIdx.x; i < F * HID; i += 256) sWa[i] = Wa[i];
    for (int i = threadIdx.x; i < HID * F; i += 256) sWb[i] = Wb[i];
    if (threadIdx.x < HID) sba[threadIdx.x] = ba[threadIdx.x];
    if (threadIdx.x < F)   sbb[threadIdx.x] = bb[threadIdx.x];
    __syncthreads();

    int node = blockIdx.x * 256 + threadIdx.x;
    float o[F];
    if (node < n_nodes) {
        float v[F];
        const float4* xp = reinterpret_cast<const float4*>(xin + (size_t)node * F);
        const float4* ap = reinterpret_cast<const float4*>(agg + (size_t)node * F);
#pragma unroll
        for (int q = 0; q < 4; q++) {
            float4 a = xp[q], b = ap[q];
            v[q * 4 + 0] = a.x + b.x;
            v[q * 4 + 1] = a.y + b.y;
            v[q * 4 + 2] = a.z + b.z;
            v[q * 4 + 3] = a.w + b.w;
        }
        float hid[HID];
#pragma unroll
        for (int j = 0; j < HID; j++) hid[j] = sba[j];
#pragma unroll
        for (int k = 0; k < F; k++) {
            float vk = v[k];
#pragma unroll
            for (int j = 0; j < HID; j++) hid[j] = fmaf(vk, sWa[k * HID + j], hid[j]);
        }
#pragma unroll
        for (int j = 0; j < HID; j++) hid[j] = fmaxf(hid[j], 0.f);
#pragma unroll
        for (int j = 0; j < F; j++) o[j] = sbb[j];
#pragma unroll
        for (int k = 0; k < HID; k++) {
            float hk = hid[k];
#pragma unroll
            for (int j = 0; j < F; j++) o[j] = fmaf(hk, sWb[k * F + j], o[j]);
        }
#pragma unroll
        for (int j = 0; j < F; j++) o[j] = fmaxf(o[j], 0.f);
        float4* op = reinterpret_cast<float4*>(hpre + (size_t)node * F);
        op[0] = make_float4(o[0], o[1], o[2], o[3]);
        op[1] = make_float4(o[4], o[5], o[6], o[7]);
        op[2] = make_float4(o[8], o[9], o[10], o[11]);
        op[3] = make_float4(o[12], o[13], o[14], o[15]);
    } else {
#pragma unroll
        for (int j = 0; j < F; j++) o[j] = 0.f;
    }

    __shared__ float red[4][2 * F];
    int lane = threadIdx.x & 63, wid = threadIdx.x >> 6;
#pragma unroll
    for (int j = 0; j < F; j++) {
        float s = o[j], ss = o[j] * o[j];
#pragma unroll
        for (int off = 32; off; off >>= 1) {
            s  += __shfl_down(s, off);
            ss += __shfl_down(ss, off);
        }
        if (lane == 0) { red[wid][j] = s; red[wid][F + j] = ss; }
    }
    __syncthreads();
    if (threadIdx.x < 2 * F) {
        float t = red[0][threadIdx.x] + red[1][threadIdx.x] +
                  red[2][threadIdx.x] + red[3][threadIdx.x];
        atomicAdd(&stats[threadIdx.x], t);
    }
}

// ---------------------------------------------------------------------------
// BN (training-mode batch stats, biased var) + ReLU.
// ---------------------------------------------------------------------------
__global__ __launch_bounds__(256) void k_bn_relu(
    const float* __restrict__ hpre, const float* __restrict__ stats,
    const float* __restrict__ gamma, const float* __restrict__ beta,
    float* __restrict__ hout, int n_nodes)
{
    int idx = blockIdx.x * 256 + threadIdx.x;
    int tot = n_nodes * 4;
    if (idx >= tot) return;
    int q = idx & 3;
    float4 v = reinterpret_cast<const float4*>(hpre)[idx];
    float invN = 1.f / (float)n_nodes;
    float r[4];
    float vin[4] = {v.x, v.y, v.z, v.w};
#pragma unroll
    for (int t = 0; t < 4; t++) {
        int j = q * 4 + t;
        float mean = stats[j] * invN;
        float var  = stats[F + j] * invN - mean * mean;
        float sc   = gamma[j] * rsqrtf(var + BN_EPS);
        r[t] = fmaxf((vin[t] - mean) * sc + beta[j], 0.f);
    }
    reinterpret_cast<float4*>(hout)[idx] = make_float4(r[0], r[1], r[2], r[3]);
}

// ---------------------------------------------------------------------------
// Per-graph max/mean pool + final FC (batch sorted; post-ReLU h >= 0).
// ---------------------------------------------------------------------------
__global__ __launch_bounds__(256) void k_pool_fc(
    const float* __restrict__ h, const int* __restrict__ batch,
    const float* __restrict__ Wfc, const float* __restrict__ bfc,
    float* __restrict__ out, int n_nodes)
{
    int g = blockIdx.x;
    int lo = 0, hi = n_nodes;
    while (lo < hi) { int m = (lo + hi) >> 1; if (batch[m] < g) lo = m + 1; else hi = m; }
    int start = lo;
    hi = n_nodes;
    while (lo < hi) { int m = (lo + hi) >> 1; if (batch[m] < g + 1) lo = m + 1; else hi = m; }
    int end = lo;

    float mx[F], sm[F];
#pragma unroll
    for (int j = 0; j < F; j++) { mx[j] = 0.f; sm[j] = 0.f; }

    for (int i = start + (int)threadIdx.x; i < end; i += 256) {
        const float4* p = reinterpret_cast<const float4*>(h + (size_t)i * F);
#pragma unroll
        for (int q = 0; q < 4; q++) {
            float4 v = p[q];
            mx[q * 4 + 0] = fmaxf(mx[q * 4 + 0], v.x); sm[q * 4 + 0] += v.x;
            mx[q * 4 + 1] = fmaxf(mx[q * 4 + 1], v.y); sm[q * 4 + 1] += v.y;
            mx[q * 4 + 2] = fmaxf(mx[q * 4 + 2], v.z); sm[q * 4 + 2] += v.z;
            mx[q * 4 + 3] = fmaxf(mx[q * 4 + 3], v.w); sm[q * 4 + 3] += v.w;
        }
    }
#pragma unroll
    for (int j = 0; j < F; j++) {
#pragma unroll
        for (int off = 32; off; off >>= 1) {
            mx[j] = fmaxf(mx[j], __shfl_down(mx[j], off));
            sm[j] += __shfl_down(sm[j], off);
        }
    }
    __shared__ float rmx[4][F], rsm[4][F];
    int lane = threadIdx.x & 63, wid = threadIdx.x >> 6;
    if (lane == 0) {
#pragma unroll
        for (int j = 0; j < F; j++) { rmx[wid][j] = mx[j]; rsm[wid][j] = sm[j]; }
    }
    __syncthreads();
    if (threadIdx.x == 0) {
        float pooled[2 * F];
        int cnt = end - start;
        float inv = 1.f / (float)(cnt > 0 ? cnt : 1);
#pragma unroll
        for (int j = 0; j < F; j++) {
            float m = fmaxf(fmaxf(rmx[0][j], rmx[1][j]), fmaxf(rmx[2][j], rmx[3][j]));
            float s = rsm[0][j] + rsm[1][j] + rsm[2][j] + rsm[3][j];
            pooled[j]     = m;
            pooled[F + j] = s * inv;
        }
#pragma unroll
        for (int c = 0; c < 2; c++) {
            float acc = bfc[c];
#pragma unroll
            for (int k = 0; k < 2 * F; k++) acc = fmaf(pooled[k], Wfc[k * 2 + c], acc);
            out[g * 2 + c] = acc;
        }
    }
}

extern "C" void kernel_launch(void* const* d_in, const int* in_sizes, int n_in,
                              void* d_out, int out_size, void* d_ws, size_t ws_size,
                              hipStream_t stream) {
    const float* x    = (const float*)d_in[0];
    const float* W1a  = (const float*)d_in[1];
    const float* b1a  = (const float*)d_in[2];
    const float* W1b  = (const float*)d_in[3];
    const float* b1b  = (const float*)d_in[4];
    const float* g1   = (const float*)d_in[5];
    const float* be1  = (const float*)d_in[6];
    const float* W2a  = (const float*)d_in[7];
    const float* b2a  = (const float*)d_in[8];
    const float* W2b  = (const float*)d_in[9];
    const float* b2b  = (const float*)d_in[10];
    const float* g2   = (const float*)d_in[11];
    const float* be2  = (const float*)d_in[12];
    const float* Wfc  = (const float*)d_in[13];
    const float* bfc  = (const float*)d_in[14];
    const int*   eidx = (const int*)d_in[15];
    const int*   batch= (const int*)d_in[16];

    const int n_nodes = in_sizes[0] / F;          // 250000
    const int n_edges = in_sizes[15] / 2;         // 8000000
    const int* src = eidx;
    const int* dst = eidx + n_edges;

    const size_t NBf = (size_t)n_nodes * F * sizeof(float);   // 16 MB
    const int nbk = (n_nodes + BSZ - 1) >> NBSHIFT;           // 245
    float* out = (float*)d_out;

    const int nblk_nodes = (n_nodes + 255) / 256;
    const int nblk_el4   = (n_nodes * 4 + 255) / 256;

    // fast-path workspace layout: [meta | part | agg | hbuf]
    size_t off = 0;
    auto take = [&](size_t bytes) { size_t o = off; off = (off + bytes + 255) & ~(size_t)255; return o; };
    size_t meta_bytes = (size_t)(3 * nbk + 2 + 64) * sizeof(unsigned);
    size_t meta_off = take(meta_bytes);
    size_t part_off = take((size_t)n_edges * sizeof(unsigned));
    size_t agg_off  = take(NBf);
    size_t hbuf_off = take(NBf);
    bool fast = (nbk <= 256) && (n_nodes <= (1 << SRCBITS)) && (off <= ws_size);

    char* ws = (char*)d_ws;
    if (fast) {
        unsigned* meta    = (unsigned*)(ws + meta_off);
        unsigned* bcnt    = meta;                 // [nbk]
        unsigned* bstart  = meta + nbk;           // [nbk+1]
        unsigned* cursor  = bstart + nbk + 1;     // [nbk]
        float*    stats1  = (float*)(cursor + nbk); // [32]
        float*    stats2  = stats1 + 32;            // [32]
        unsigned* part    = (unsigned*)(ws + part_off);
        float*    agg     = (float*)(ws + agg_off);
        float*    hbuf    = (float*)(ws + hbuf_off);

        hipMemsetAsync(meta, 0, meta_bytes, stream);
        k_hist<<<1024, 256, 0, stream>>>(dst, n_edges, bcnt, nbk);
        k_scan<<<1, 64, 0, stream>>>(bcnt, bstart, cursor, nbk);
        int npart = (n_edges + PCHUNK - 1) / PCHUNK;
        k_partition<<<npart, 256, 0, stream>>>(src, dst, n_edges, cursor, part, nbk);

        // ---- layer 1 ----
        k_aggregate<<<nbk, 1024, 0, stream>>>(x, part, bstart, agg, n_nodes);
        k_mlp_stats<32><<<nblk_nodes, 256, 0, stream>>>(x, agg, W1a, b1a, W1b, b1b,
                                                        agg /*in-place*/, stats1, n_nodes);
        k_bn_relu<<<nblk_el4, 256, 0, stream>>>(agg, stats1, g1, be1, hbuf, n_nodes);

        // ---- layer 2 (partition reused) ----
        k_aggregate<<<nbk, 1024, 0, stream>>>(hbuf, part, bstart, agg, n_nodes);
        k_mlp_stats<16><<<nblk_nodes, 256, 0, stream>>>(hbuf, agg, W2a, b2a, W2b, b2b,
                                                        agg /*in-place*/, stats2, n_nodes);
        k_bn_relu<<<nblk_el4, 256, 0, stream>>>(agg, stats2, g2, be2, hbuf, n_nodes);

        k_pool_fc<<<N_GRAPHS_C, 256, 0, stream>>>(hbuf, batch, Wfc, bfc, out, n_nodes);
    } else {
        // fallback: original atomic-scatter pipeline
        float* hpre = (float*)(ws);
        float* hbuf = (float*)(ws + NBf);
        float* agg  = (float*)(ws + 2 * NBf);
        float* stats= (float*)(ws + 3 * NBf);
        const int nblk_edges = (int)(((long long)n_edges * 4 + 255) / 256);

        hipMemsetAsync(agg, 0, NBf, stream);
        hipMemsetAsync(stats, 0, 2 * F * sizeof(float), stream);
        k_scatter<<<nblk_edges, 256, 0, stream>>>(x, src, dst, agg, n_edges);
        k_mlp_stats<32><<<nblk_nodes, 256, 0, stream>>>(x, agg, W1a, b1a, W1b, b1b,
                                                        hpre, stats, n_nodes);
        k_bn_relu<<<nblk_el4, 256, 0, stream>>>(hpre, stats, g1, be1, hbuf, n_nodes);

        hipMemsetAsync(agg, 0, NBf, stream);
        hipMemsetAsync(stats, 0, 2 * F * sizeof(float), stream);
        k_scatter<<<nblk_edges, 256, 0, stream>>>(hbuf, src, dst, agg, n_edges);
        k_mlp_stats<16><<<nblk_nodes, 256, 0, stream>>>(hbuf, agg, W2a, b2a, W2b, b2b,
                                                        hpre, stats, n_nodes);
        k_bn_relu<<<nblk_el4, 256, 0, stream>>>(hpre, stats, g2, be2, hbuf, n_nodes);

        k_pool_fc<<<N_GRAPHS_C, 256, 0, stream>>>(hbuf, batch, Wfc, bfc, out, n_nodes);
    }
}